// Round 1
// baseline (1450.824 us; speedup 1.0000x reference)
//
#include <hip/hip_runtime.h>

typedef short s16x8 __attribute__((ext_vector_type(8)));
typedef short s16x4 __attribute__((ext_vector_type(4)));
typedef float f32x4 __attribute__((ext_vector_type(4)));

#define CH 64
#define TSEQ 4096
#define TOUT 2048
#define NBLK 4
#define COLS 112          // columns per tile (7 n-tiles of 16)
#define TT 106            // owned output timesteps per tile
#define HALO 6
#define NTILE 39          // ceil(4096/106)
#define NT 7              // n-tiles
#define GBROW 72          // bf16 row stride: 144B, 16B-aligned, 36 dw = 4 mod 32 -> uniform banks
#define QPT 53            // dilated outputs per tile
#define DIL_TOTAL 33554432

// d_ws layout: shorts (bf16) then floats
#define WA_OFF 0          // [blk4][mat2][half2][kc2][tap2][h64][c-chunk32] bf16
#define WO_OFF 131072     // [blk4][half2][kc2][c64][h-chunk32]
#define WD_OFF 163840     // [half2][kc2][tap2][co64][ci-chunk32]
#define SK_BYTE_OFF 360448 // fp32 [ci64][o64]

__device__ __forceinline__ short f2bf(float x) {     // RNE fp32->bf16
  unsigned u = __float_as_uint(x);
  return (short)((u + 0x7fffu + ((u >> 16) & 1u)) >> 16);
}
__device__ __forceinline__ float bf2f(short h) {
  return __uint_as_float(((unsigned)(unsigned short)h) << 16);
}
__device__ __forceinline__ f32x4 mfma16(s16x8 a, s16x8 b, f32x4 c) {
  return __builtin_amdgcn_mfma_f32_16x16x32_bf16(a, b, c, 0, 0, 0);
}

__global__ void prep(const float* __restrict__ sig_w, const float* __restrict__ gate_w,
                     const float* __restrict__ out_w, const float* __restrict__ dil_w,
                     const float* __restrict__ skip_w, short* __restrict__ wsS,
                     float* __restrict__ wsF) {
  const int idx = blockIdx.x * 256 + threadIdx.x;
  if (idx < 131072) {                       // WA: sig/gate conv weights
    const int inner = idx & 2047, grp = idx >> 11;
    const int tap = grp & 1, kc = (grp >> 1) & 1, half = (grp >> 2) & 1;
    const int mat = (grp >> 3) & 1, blk = grp >> 4;
    const int h = inner >> 5, c = kc * 32 + (inner & 31);
    const float* W = mat ? gate_w : sig_w;
    const float w = W[((blk * CH + h) * CH + c) * 2 + tap];
    const short hi = f2bf(w);
    wsS[WA_OFF + idx] = half ? f2bf(w - bf2f(hi)) : hi;
  } else if (idx < 163840) {                // WO: 1x1 out conv
    const int i2 = idx - 131072;
    const int inner = i2 & 2047, grp = i2 >> 11;
    const int kc = grp & 1, half = (grp >> 1) & 1, blk = grp >> 2;
    const int c = inner >> 5, h = kc * 32 + (inner & 31);
    const float w = out_w[(blk * CH + c) * CH + h];
    const short hi = f2bf(w);
    wsS[idx] = half ? f2bf(w - bf2f(hi)) : hi;
  } else if (idx < 180224) {                // WD: dilated conv
    const int i3 = idx - 163840;
    const int inner = i3 & 2047, grp = i3 >> 11;
    const int tap = grp & 1, kc = (grp >> 1) & 1, half = (grp >> 2) & 1;
    const int co = inner >> 5, ci = kc * 32 + (inner & 31);
    const float w = dil_w[(co * CH + ci) * 2 + tap];
    const short hi = f2bf(w);
    wsS[idx] = half ? f2bf(w - bf2f(hi)) : hi;
  } else if (idx < 184320) {                // SK: skip weights, fp32 transposed
    const int i4 = idx - 180224;
    const int ci = i4 >> 6, o = i4 & 63;
    wsF[i4] = skip_w[o * CH + ci];
  }
}

// Residual master lives in REGISTERS (gReg), not LDS: each thread owns the
// fp32 residual for exactly its epilogue fragment (c = hbase+g4*4+r,
// p = j*16+n).  LDS holds only the bf16 hi/lo tile (32.8 KB) -> 4 wg/CU.
__global__ __launch_bounds__(256, 4)
void wavenet_mfma(const float* __restrict__ x,
                  const float* __restrict__ sig_b, const float* __restrict__ gate_b,
                  const float* __restrict__ out_b, const float* __restrict__ skip_b,
                  const float* __restrict__ dil_b, const short* __restrict__ wsS,
                  const float* __restrict__ wsF, float* __restrict__ out) {
  __shared__ __align__(16) short GBs[2 * 113 * GBROW];    // bf16 hi/lo [half][r=p+1][c]; shared with U
  __shared__ __align__(16) float skipBuf[CH];             // last-timestep residual for skip conv

  const int tile = blockIdx.x % NTILE;
  const int b    = blockIdx.x / NTILE;
  const int t0   = tile * TT;
  const int tid  = threadIdx.x;
  const int lane = tid & 63;
  const int wv   = tid >> 6;
  const int n    = lane & 15;          // n / D-col index
  const int g4   = lane >> 4;          // quad id
  const int hbase = wv * 16;           // this wave's m-strip
  const int cch  = hbase + g4 * 4;     // this thread's 4-channel strip

  f32x4 gReg[NT];                      // fp32 residual master, fragment layout

  // ---- x -> gReg (fp32) + GB (bf16 hi/lo), causal zero-pad outside [0,T) ----
  {
    const float* xb = x + ((size_t)(b * CH + cch)) * TSEQ;
#pragma unroll
    for (int j = 0; j < NT; ++j) {
      const int p = j * 16 + n;
      const int tg = t0 - HALO + p;
      f32x4 v = (f32x4)0.f;
      if (tg >= 0 && tg < TSEQ) {
        v[0] = xb[tg];
        v[1] = xb[TSEQ + tg];
        v[2] = xb[2 * TSEQ + tg];
        v[3] = xb[3 * TSEQ + tg];
      }
      gReg[j] = v;
      s16x4 nh, nl;
#pragma unroll
      for (int r = 0; r < 4; ++r) {
        const short hi = f2bf(v[r]);
        nh[r] = hi; nl[r] = f2bf(v[r] - bf2f(hi));
      }
      *(s16x4*)&GBs[(p + 1) * GBROW + cch] = nh;
      *(s16x4*)&GBs[(113 + p + 1) * GBROW + cch] = nl;
    }
  }
  if (tid < 2 * GBROW) {               // row 0 = p=-1 (zero pad)
    const int half = tid / GBROW;
    GBs[half * 113 * GBROW + (tid - half * GBROW)] = 0;
  }
  __syncthreads();

  // B-fragment base pointers: row = n + tap (+ n-tile/kc via immediates)
  const short* bpH0 = &GBs[(n + 0) * GBROW + g4 * 8];
  const short* bpH1 = &GBs[(n + 1) * GBROW + g4 * 8];
  const short* bpL0 = &GBs[(113 + n + 0) * GBROW + g4 * 8];
  const short* bpL1 = &GBs[(113 + n + 1) * GBROW + g4 * 8];
  const int lo_p = (tile == 0) ? HALO : 0;   // tile 0 keeps t<0 columns pinned to 0
  const int lbase = (hbase + n) * 32 + g4 * 8;   // A-frag lane offset

#pragma unroll 1
  for (int blk = 0; blk < NBLK; ++blk) {
    // ---- A-fragments (sig/gate weights) from prepped global, frag-ordered ----
    s16x8 wS[2][2][2], wG[2][2][2];   // [half][kc][tap]
#pragma unroll
    for (int half = 0; half < 2; ++half)
#pragma unroll
      for (int kc = 0; kc < 2; ++kc)
#pragma unroll
        for (int tap = 0; tap < 2; ++tap) {
          wS[half][kc][tap] = *(const s16x8*)&wsS[WA_OFF + ((((blk*2+0)*2+half)*2+kc)*2+tap)*2048 + lbase];
          wG[half][kc][tap] = *(const s16x8*)&wsS[WA_OFF + ((((blk*2+1)*2+half)*2+kc)*2+tap)*2048 + lbase];
        }

    // ---- GEMM1: S,T[h=16-strip][p] via split-bf16 (HH + LH + HL) ----
    f32x4 aS[NT], aG[NT];
#pragma unroll
    for (int j = 0; j < NT; ++j) { aS[j] = (f32x4)0.f; aG[j] = (f32x4)0.f; }
#pragma unroll
    for (int j = 0; j < NT; ++j) {
      const int ro = j * 16 * GBROW;
#pragma unroll
      for (int kc = 0; kc < 2; ++kc) {
        const int co = ro + kc * 32;
        {
          const s16x8 bh = *(const s16x8*)(bpH0 + co);
          const s16x8 bl = *(const s16x8*)(bpL0 + co);
          aS[j] = mfma16(wS[0][kc][0], bh, aS[j]);
          aS[j] = mfma16(wS[1][kc][0], bh, aS[j]);
          aS[j] = mfma16(wS[0][kc][0], bl, aS[j]);
          aG[j] = mfma16(wG[0][kc][0], bh, aG[j]);
          aG[j] = mfma16(wG[1][kc][0], bh, aG[j]);
          aG[j] = mfma16(wG[0][kc][0], bl, aG[j]);
        }
        {
          const s16x8 bh = *(const s16x8*)(bpH1 + co);
          const s16x8 bl = *(const s16x8*)(bpL1 + co);
          aS[j] = mfma16(wS[0][kc][1], bh, aS[j]);
          aS[j] = mfma16(wS[1][kc][1], bh, aS[j]);
          aS[j] = mfma16(wS[0][kc][1], bl, aS[j]);
          aG[j] = mfma16(wG[0][kc][1], bh, aG[j]);
          aG[j] = mfma16(wG[1][kc][1], bh, aG[j]);
          aG[j] = mfma16(wG[0][kc][1], bl, aG[j]);
        }
      }
    }
    __syncthreads();   // GEMM1 reads of GB done

    // ---- elementwise: U = relu(S+bs)*sigmoid(T+bg); write U hi/lo over GB ----
    const f32x4 bs4 = *(const f32x4*)(sig_b  + blk * 64 + cch);
    const f32x4 bg4 = *(const f32x4*)(gate_b + blk * 64 + cch);
#pragma unroll
    for (int j = 0; j < NT; ++j) {
      s16x4 uh, ul;
#pragma unroll
      for (int r = 0; r < 4; ++r) {
        const float s = fmaxf(aS[j][r] + bs4[r], 0.f);
        const float t = aG[j][r] + bg4[r];
        const float u = s * __builtin_amdgcn_rcpf(1.f + __expf(-t));
        const short hi = f2bf(u);
        uh[r] = hi; ul[r] = f2bf(u - bf2f(hi));
      }
      const int r1 = j * 16 + n + 1;
      *(s16x4*)&GBs[r1 * GBROW + cch] = uh;
      *(s16x4*)&GBs[(113 + r1) * GBROW + cch] = ul;
    }
    __syncthreads();   // U complete

    // ---- GEMM2: dG[c=16-strip][p] = b_out + Wout * U ----
    s16x8 wO2[2][2];   // [half][kc] — loaded late to shorten live range
#pragma unroll
    for (int half = 0; half < 2; ++half)
#pragma unroll
      for (int kc = 0; kc < 2; ++kc)
        wO2[half][kc] = *(const s16x8*)&wsS[WO_OFF + ((blk*2+half)*2+kc)*2048 + lbase];
    f32x4 aO[NT];
    const f32x4 ob4 = *(const f32x4*)(out_b + blk * 64 + cch);
#pragma unroll
    for (int j = 0; j < NT; ++j) aO[j] = ob4;
#pragma unroll
    for (int j = 0; j < NT; ++j) {
      const int ro = j * 16 * GBROW;
#pragma unroll
      for (int kc = 0; kc < 2; ++kc) {
        const s16x8 uh = *(const s16x8*)(bpH1 + ro + kc * 32);
        const s16x8 ul = *(const s16x8*)(bpL1 + ro + kc * 32);
        aO[j] = mfma16(wO2[0][kc], uh, aO[j]);
        aO[j] = mfma16(wO2[1][kc], uh, aO[j]);
        aO[j] = mfma16(wO2[0][kc], ul, aO[j]);
      }
    }
    __syncthreads();   // GEMM2 reads of U done

    // ---- epilogue: residual update in fp32 registers + re-split into GB ----
#pragma unroll
    for (int j = 0; j < NT; ++j) {
      const int p = j * 16 + n;
      const f32x4 nv = (p >= lo_p) ? (f32x4)(gReg[j] + aO[j]) : gReg[j];
      gReg[j] = nv;
      s16x4 nh, nl;
#pragma unroll
      for (int r = 0; r < 4; ++r) {
        const short hi = f2bf(nv[r]);
        nh[r] = hi; nl[r] = f2bf(nv[r] - bf2f(hi));
      }
      *(s16x4*)&GBs[(p + 1) * GBROW + cch] = nh;
      *(s16x4*)&GBs[(113 + p + 1) * GBROW + cch] = nl;
    }
    __syncthreads();
  }

  // ---- publish last-timestep residual for skip (p=4095-4028+6=73 -> j=4,n=9) ----
  if (tile == NTILE - 1 && n == 9) {
    *(f32x4*)&skipBuf[cch] = gReg[4];
  }

  // ---- dilated stride-2 conv (GEMM over tau) ----
  {
    s16x8 wD[2][2][2];
#pragma unroll
    for (int half = 0; half < 2; ++half)
#pragma unroll
      for (int kc = 0; kc < 2; ++kc)
#pragma unroll
        for (int tap = 0; tap < 2; ++tap)
          wD[half][kc][tap] = *(const s16x8*)&wsS[WD_OFF + ((half*2+kc)*2+tap)*2048 + lbase];
    const f32x4 db4 = *(const f32x4*)(dil_b + cch);
    const int tau0 = tile * QPT;
#pragma unroll
    for (int j = 0; j < 4; ++j) {
      const int idx = j * 16 + n;
      const int idxc = (idx < QPT) ? idx : (QPT - 1);   // clamp reads; stores masked
      f32x4 ad = db4;
      const int rbase = (6 + idxc * 2) * GBROW + g4 * 8;
#pragma unroll
      for (int kc = 0; kc < 2; ++kc)
#pragma unroll
        for (int tap = 0; tap < 2; ++tap) {
          const s16x8 bh = *(const s16x8*)&GBs[rbase + tap * GBROW + kc * 32];
          const s16x8 bl = *(const s16x8*)&GBs[113 * GBROW + rbase + tap * GBROW + kc * 32];
          ad = mfma16(wD[0][kc][tap], bh, ad);
          ad = mfma16(wD[1][kc][tap], bh, ad);
          ad = mfma16(wD[0][kc][tap], bl, ad);
        }
      const int tau = tau0 + idx;
      if (idx < QPT && tau < TOUT) {
        const int cobase = b * CH + cch;
#pragma unroll
        for (int r = 0; r < 4; ++r)
          out[(cobase + r) * TOUT + tau] = ad[r];
      }
    }
  }

  // ---- skip: 1x1 conv on t=4095, exact fp32 from skipBuf ----
  if (tile == NTILE - 1) {
    __syncthreads();   // skipBuf visible (uniform branch: tile is wg-uniform)
    if (wv == 0) {
      const int o = lane;
      float a = skip_b[o];
      for (int c = 0; c < CH; ++c)
        a = fmaf(wsF[c * CH + o], skipBuf[c], a);
      out[DIL_TOTAL + b * CH + o] = a;
    }
  }
}

extern "C" void kernel_launch(void* const* d_in, const int* in_sizes, int n_in,
                              void* d_out, int out_size, void* d_ws, size_t ws_size,
                              hipStream_t stream) {
  const float* x      = (const float*)d_in[0];
  const float* sig_w  = (const float*)d_in[1];
  const float* sig_b  = (const float*)d_in[2];
  const float* gate_w = (const float*)d_in[3];
  const float* gate_b = (const float*)d_in[4];
  const float* out_w  = (const float*)d_in[5];
  const float* out_b  = (const float*)d_in[6];
  const float* skip_w = (const float*)d_in[7];
  const float* skip_b = (const float*)d_in[8];
  const float* dil_w  = (const float*)d_in[9];
  const float* dil_b  = (const float*)d_in[10];
  short* wsS = (short*)d_ws;
  float* wsF = (float*)((char*)d_ws + SK_BYTE_OFF);
  float* out = (float*)d_out;

  prep<<<dim3(720), dim3(256), 0, stream>>>(sig_w, gate_w, out_w, dil_w, skip_w, wsS, wsF);
  wavenet_mfma<<<dim3(256 * NTILE), dim3(256), 0, stream>>>(
      x, sig_b, gate_b, out_b, skip_b, dil_b, (const short*)wsS, (const float*)wsF, out);
}

// Round 3
// 1115.637 us; speedup vs baseline: 1.3004x; 1.3004x over previous
//
#include <hip/hip_runtime.h>

typedef short s16x8 __attribute__((ext_vector_type(8)));
typedef short s16x4 __attribute__((ext_vector_type(4)));
typedef float f32x4 __attribute__((ext_vector_type(4)));

#define CH 64
#define TSEQ 4096
#define TOUT 2048
#define NBLK 4
#define COLS 112          // columns per tile (7 n-tiles of 16)
#define TT 106            // owned output timesteps per tile
#define HALO 6
#define NTILE 39          // ceil(4096/106)
#define NT 7              // n-tiles
#define GBROW 72          // bf16 row stride: 144B, 16B-aligned, 36 dw = 4 mod 32 -> uniform banks
#define QPT 53            // dilated outputs per tile
#define DIL_TOTAL 33554432

// d_ws layout: shorts (bf16) then floats
#define WA_OFF 0          // [blk4][mat2][half2][kc2][tap2][h64][c-chunk32] bf16
#define WO_OFF 131072     // [blk4][half2][kc2][c64][h-chunk32]
#define WD_OFF 163840     // [half2][kc2][tap2][co64][ci-chunk32]
#define SK_BYTE_OFF 360448 // fp32 [ci64][o64]

__device__ __forceinline__ short f2bf(float x) {     // RNE fp32->bf16
  unsigned u = __float_as_uint(x);
  return (short)((u + 0x7fffu + ((u >> 16) & 1u)) >> 16);
}
__device__ __forceinline__ float bf2f(short h) {
  return __uint_as_float(((unsigned)(unsigned short)h) << 16);
}
__device__ __forceinline__ f32x4 mfma16(s16x8 a, s16x8 b, f32x4 c) {
  return __builtin_amdgcn_mfma_f32_16x16x32_bf16(a, b, c, 0, 0, 0);
}

__global__ void prep(const float* __restrict__ sig_w, const float* __restrict__ gate_w,
                     const float* __restrict__ out_w, const float* __restrict__ dil_w,
                     const float* __restrict__ skip_w, short* __restrict__ wsS,
                     float* __restrict__ wsF) {
  const int idx = blockIdx.x * 256 + threadIdx.x;
  if (idx < 131072) {                       // WA: sig/gate conv weights
    const int inner = idx & 2047, grp = idx >> 11;
    const int tap = grp & 1, kc = (grp >> 1) & 1, half = (grp >> 2) & 1;
    const int mat = (grp >> 3) & 1, blk = grp >> 4;
    const int h = inner >> 5, c = kc * 32 + (inner & 31);
    const float* W = mat ? gate_w : sig_w;
    const float w = W[((blk * CH + h) * CH + c) * 2 + tap];
    const short hi = f2bf(w);
    wsS[WA_OFF + idx] = half ? f2bf(w - bf2f(hi)) : hi;
  } else if (idx < 163840) {                // WO: 1x1 out conv
    const int i2 = idx - 131072;
    const int inner = i2 & 2047, grp = i2 >> 11;
    const int kc = grp & 1, half = (grp >> 1) & 1, blk = grp >> 2;
    const int c = inner >> 5, h = kc * 32 + (inner & 31);
    const float w = out_w[(blk * CH + c) * CH + h];
    const short hi = f2bf(w);
    wsS[idx] = half ? f2bf(w - bf2f(hi)) : hi;
  } else if (idx < 180224) {                // WD: dilated conv
    const int i3 = idx - 163840;
    const int inner = i3 & 2047, grp = i3 >> 11;
    const int tap = grp & 1, kc = (grp >> 1) & 1, half = (grp >> 2) & 1;
    const int co = inner >> 5, ci = kc * 32 + (inner & 31);
    const float w = dil_w[(co * CH + ci) * 2 + tap];
    const short hi = f2bf(w);
    wsS[idx] = half ? f2bf(w - bf2f(hi)) : hi;
  } else if (idx < 184320) {                // SK: skip weights, fp32 transposed
    const int i4 = idx - 180224;
    const int ci = i4 >> 6, o = i4 & 63;
    wsF[i4] = skip_w[o * CH + ci];
  }
}

// Residual master: 3-component bf16 split (hi/lo in GBs, e3 in GEs) ~= fp32.
// No fp32 LDS master, no registers held across GEMM1: old-g is re-read from
// the thread's OWN LDS fragment locations at elementwise time (just before U
// overwrites them) and lives only through GEMM2 (low-pressure phase).
// LDS ~49 KB + VGPR<=168 -> 3 wg/CU (vs 2 before; round-1's 4-wg attempt
// held gReg across GEMM1 and spilled 4.4 GB to scratch).
__global__ __launch_bounds__(256, 3)
void wavenet_mfma(const float* __restrict__ x,
                  const float* __restrict__ sig_b, const float* __restrict__ gate_b,
                  const float* __restrict__ out_b, const float* __restrict__ skip_b,
                  const float* __restrict__ dil_b, const short* __restrict__ wsS,
                  const float* __restrict__ wsF, float* __restrict__ out) {
  __shared__ __align__(16) short GBs[2 * 113 * GBROW];    // bf16 hi/lo [half][r=p+1][c]; shared with U
  __shared__ __align__(16) short GEs[113 * GBROW];        // bf16 e3 (3rd split component of residual)

  const int tile = blockIdx.x % NTILE;
  const int b    = blockIdx.x / NTILE;
  const int t0   = tile * TT;
  const int tid  = threadIdx.x;
  const int lane = tid & 63;
  const int wv   = tid >> 6;
  const int n    = lane & 15;          // n / D-col index
  const int g4   = lane >> 4;          // quad id
  const int hbase = wv * 16;           // this wave's m-strip
  const int cch  = hbase + g4 * 4;     // this thread's 4-channel strip

  // ---- x -> GB (bf16 hi/lo) + GE (e3), causal zero-pad outside [0,T) ----
  for (int idx = tid; idx < CH * COLS; idx += 256) {
    const int c = idx / COLS, p = idx - c * COLS;
    const int tg = t0 - HALO + p;
    float v = 0.f;
    if (tg >= 0 && tg < TSEQ) v = x[(b * CH + c) * TSEQ + tg];
    const short hi = f2bf(v);
    const float lf = v - bf2f(hi);
    const short lo = f2bf(lf);
    GBs[(p + 1) * GBROW + c] = hi;
    GBs[(113 + p + 1) * GBROW + c] = lo;
    GEs[(p + 1) * GBROW + c] = f2bf(lf - bf2f(lo));
  }
  if (tid < 2 * GBROW) {               // row 0 = p=-1 (zero pad)
    const int half = tid / GBROW;
    GBs[half * 113 * GBROW + (tid - half * GBROW)] = 0;
  } else if (tid < 3 * GBROW) {
    GEs[tid - 2 * GBROW] = 0;
  }
  __syncthreads();

  // B-fragment base pointers: row = n + tap (+ n-tile/kc via immediates)
  const short* bpH0 = &GBs[(n + 0) * GBROW + g4 * 8];
  const short* bpH1 = &GBs[(n + 1) * GBROW + g4 * 8];
  const short* bpL0 = &GBs[(113 + n + 0) * GBROW + g4 * 8];
  const short* bpL1 = &GBs[(113 + n + 1) * GBROW + g4 * 8];
  const int lo_p = (tile == 0) ? HALO : 0;   // tile 0 keeps t<0 columns pinned to 0
  const int lbase = (hbase + n) * 32 + g4 * 8;   // A-frag lane offset

#pragma unroll 1
  for (int blk = 0; blk < NBLK; ++blk) {
    // ---- A-fragments (sig/gate weights) from prepped global, frag-ordered ----
    s16x8 wS[2][2][2], wG[2][2][2];   // [half][kc][tap]
#pragma unroll
    for (int half = 0; half < 2; ++half)
#pragma unroll
      for (int kc = 0; kc < 2; ++kc)
#pragma unroll
        for (int tap = 0; tap < 2; ++tap) {
          wS[half][kc][tap] = *(const s16x8*)&wsS[WA_OFF + ((((blk*2+0)*2+half)*2+kc)*2+tap)*2048 + lbase];
          wG[half][kc][tap] = *(const s16x8*)&wsS[WA_OFF + ((((blk*2+1)*2+half)*2+kc)*2+tap)*2048 + lbase];
        }

    // ---- GEMM1: S,T[h=16-strip][p] via split-bf16 (HH + LH + HL) ----
    f32x4 aS[NT], aG[NT];
#pragma unroll
    for (int j = 0; j < NT; ++j) { aS[j] = (f32x4)0.f; aG[j] = (f32x4)0.f; }
#pragma unroll
    for (int j = 0; j < NT; ++j) {
      const int ro = j * 16 * GBROW;
#pragma unroll
      for (int kc = 0; kc < 2; ++kc) {
        const int co = ro + kc * 32;
        {
          const s16x8 bh = *(const s16x8*)(bpH0 + co);
          const s16x8 bl = *(const s16x8*)(bpL0 + co);
          aS[j] = mfma16(wS[0][kc][0], bh, aS[j]);
          aS[j] = mfma16(wS[1][kc][0], bh, aS[j]);
          aS[j] = mfma16(wS[0][kc][0], bl, aS[j]);
          aG[j] = mfma16(wG[0][kc][0], bh, aG[j]);
          aG[j] = mfma16(wG[1][kc][0], bh, aG[j]);
          aG[j] = mfma16(wG[0][kc][0], bl, aG[j]);
        }
        {
          const s16x8 bh = *(const s16x8*)(bpH1 + co);
          const s16x8 bl = *(const s16x8*)(bpL1 + co);
          aS[j] = mfma16(wS[0][kc][1], bh, aS[j]);
          aS[j] = mfma16(wS[1][kc][1], bh, aS[j]);
          aS[j] = mfma16(wS[0][kc][1], bl, aS[j]);
          aG[j] = mfma16(wG[0][kc][1], bh, aG[j]);
          aG[j] = mfma16(wG[1][kc][1], bh, aG[j]);
          aG[j] = mfma16(wG[0][kc][1], bl, aG[j]);
        }
      }
    }
    __syncthreads();   // GEMM1 reads of GB done

    // ---- elementwise: read old-g (before overwrite!), then U over GB ----
    f32x4 gOld[NT];    // live only through GEMM2 (low-pressure phase)
    const f32x4 bs4 = *(const f32x4*)(sig_b  + blk * 64 + cch);
    const f32x4 bg4 = *(const f32x4*)(gate_b + blk * 64 + cch);
#pragma unroll
    for (int j = 0; j < NT; ++j) {
      const int r1 = j * 16 + n + 1;
      const s16x4 oh = *(const s16x4*)&GBs[r1 * GBROW + cch];
      const s16x4 ol = *(const s16x4*)&GBs[(113 + r1) * GBROW + cch];
      const s16x4 oe = *(const s16x4*)&GEs[r1 * GBROW + cch];
      s16x4 uh, ul;
#pragma unroll
      for (int r = 0; r < 4; ++r) {
        gOld[j][r] = bf2f(oh[r]) + bf2f(ol[r]) + bf2f(oe[r]);
        const float s = fmaxf(aS[j][r] + bs4[r], 0.f);
        const float t = aG[j][r] + bg4[r];
        const float u = s * __builtin_amdgcn_rcpf(1.f + __expf(-t));
        const short hi = f2bf(u);
        uh[r] = hi; ul[r] = f2bf(u - bf2f(hi));
      }
      *(s16x4*)&GBs[r1 * GBROW + cch] = uh;
      *(s16x4*)&GBs[(113 + r1) * GBROW + cch] = ul;
    }
    __syncthreads();   // U complete

    // ---- GEMM2: dG[c=16-strip][p] = b_out + Wout * U ----
    s16x8 wO2[2][2];   // [half][kc] — loaded late to shorten live range
#pragma unroll
    for (int half = 0; half < 2; ++half)
#pragma unroll
      for (int kc = 0; kc < 2; ++kc)
        wO2[half][kc] = *(const s16x8*)&wsS[WO_OFF + ((blk*2+half)*2+kc)*2048 + lbase];
    f32x4 aO[NT];
    const f32x4 ob4 = *(const f32x4*)(out_b + blk * 64 + cch);
#pragma unroll
    for (int j = 0; j < NT; ++j) aO[j] = ob4;
#pragma unroll
    for (int j = 0; j < NT; ++j) {
      const int ro = j * 16 * GBROW;
#pragma unroll
      for (int kc = 0; kc < 2; ++kc) {
        const s16x8 uh = *(const s16x8*)(bpH1 + ro + kc * 32);
        const s16x8 ul = *(const s16x8*)(bpL1 + ro + kc * 32);
        aO[j] = mfma16(wO2[0][kc], uh, aO[j]);
        aO[j] = mfma16(wO2[1][kc], uh, aO[j]);
        aO[j] = mfma16(wO2[0][kc], ul, aO[j]);
      }
    }
    __syncthreads();   // GEMM2 reads of U done

    // ---- epilogue: residual update in fp32 + re-split (hi/lo/e3) into LDS ----
#pragma unroll
    for (int j = 0; j < NT; ++j) {
      const int p = j * 16 + n;
      const f32x4 nv = (p >= lo_p) ? (f32x4)(gOld[j] + aO[j]) : gOld[j];
      s16x4 nh, nl, ne;
#pragma unroll
      for (int r = 0; r < 4; ++r) {
        const short hi = f2bf(nv[r]);
        const float lf = nv[r] - bf2f(hi);
        const short lo = f2bf(lf);
        nh[r] = hi; nl[r] = lo; ne[r] = f2bf(lf - bf2f(lo));
      }
      *(s16x4*)&GBs[(p + 1) * GBROW + cch] = nh;
      *(s16x4*)&GBs[(113 + p + 1) * GBROW + cch] = nl;
      *(s16x4*)&GEs[(p + 1) * GBROW + cch] = ne;
    }
    __syncthreads();
  }

  // ---- dilated stride-2 conv (GEMM over tau) ----
  {
    s16x8 wD[2][2][2];
#pragma unroll
    for (int half = 0; half < 2; ++half)
#pragma unroll
      for (int kc = 0; kc < 2; ++kc)
#pragma unroll
        for (int tap = 0; tap < 2; ++tap)
          wD[half][kc][tap] = *(const s16x8*)&wsS[WD_OFF + ((half*2+kc)*2+tap)*2048 + lbase];
    const f32x4 db4 = *(const f32x4*)(dil_b + cch);
    const int tau0 = tile * QPT;
#pragma unroll
    for (int j = 0; j < 4; ++j) {
      const int idx = j * 16 + n;
      const int idxc = (idx < QPT) ? idx : (QPT - 1);   // clamp reads; stores masked
      f32x4 ad = db4;
      const int rbase = (6 + idxc * 2) * GBROW + g4 * 8;
#pragma unroll
      for (int kc = 0; kc < 2; ++kc)
#pragma unroll
        for (int tap = 0; tap < 2; ++tap) {
          const s16x8 bh = *(const s16x8*)&GBs[rbase + tap * GBROW + kc * 32];
          const s16x8 bl = *(const s16x8*)&GBs[113 * GBROW + rbase + tap * GBROW + kc * 32];
          ad = mfma16(wD[0][kc][tap], bh, ad);
          ad = mfma16(wD[1][kc][tap], bh, ad);
          ad = mfma16(wD[0][kc][tap], bl, ad);
        }
      const int tau = tau0 + idx;
      if (idx < QPT && tau < TOUT) {
        const int cobase = b * CH + cch;
#pragma unroll
        for (int r = 0; r < 4; ++r)
          out[(cobase + r) * TOUT + tau] = ad[r];
      }
    }
  }

  // ---- skip: 1x1 conv on t=4095 (p=73 -> row 74), 3-component reconstruct ----
  if (tile == NTILE - 1 && wv == 0) {
    const int o = lane;
    float a = skip_b[o];
    for (int c = 0; c < CH; ++c) {
      const float g = bf2f(GBs[74 * GBROW + c]) + bf2f(GBs[(113 + 74) * GBROW + c])
                    + bf2f(GEs[74 * GBROW + c]);
      a = fmaf(wsF[c * CH + o], g, a);
    }
    out[DIL_TOTAL + b * CH + o] = a;
  }
}

extern "C" void kernel_launch(void* const* d_in, const int* in_sizes, int n_in,
                              void* d_out, int out_size, void* d_ws, size_t ws_size,
                              hipStream_t stream) {
  const float* x      = (const float*)d_in[0];
  const float* sig_w  = (const float*)d_in[1];
  const float* sig_b  = (const float*)d_in[2];
  const float* gate_w = (const float*)d_in[3];
  const float* gate_b = (const float*)d_in[4];
  const float* out_w  = (const float*)d_in[5];
  const float* out_b  = (const float*)d_in[6];
  const float* skip_w = (const float*)d_in[7];
  const float* skip_b = (const float*)d_in[8];
  const float* dil_w  = (const float*)d_in[9];
  const float* dil_b  = (const float*)d_in[10];
  short* wsS = (short*)d_ws;
  float* wsF = (float*)((char*)d_ws + SK_BYTE_OFF);
  float* out = (float*)d_out;

  prep<<<dim3(720), dim3(256), 0, stream>>>(sig_w, gate_w, out_w, dil_w, skip_w, wsS, wsF);
  wavenet_mfma<<<dim3(256 * NTILE), dim3(256), 0, stream>>>(
      x, sig_b, gate_b, out_b, skip_b, dil_b, (const short*)wsS, (const float*)wsF, out);
}

// Round 5
// 967.563 us; speedup vs baseline: 1.4995x; 1.1530x over previous
//
#include <hip/hip_runtime.h>

typedef short s16x8 __attribute__((ext_vector_type(8)));
typedef short s16x4 __attribute__((ext_vector_type(4)));
typedef float f32x4 __attribute__((ext_vector_type(4)));

#define CH 64
#define TSEQ 4096
#define TOUT 2048
#define NBLK 4
#define COLS 112          // columns per tile (7 n-tiles of 16)
#define TT 106            // owned output timesteps per tile
#define HALO 6
#define NTILE 39          // ceil(4096/106)
#define NT 7              // n-tiles
#define GBROW 72          // bf16 row stride: 144B, 16B-aligned, 36 dw = 4 mod 32 -> uniform banks
#define QPT 53            // dilated outputs per tile
#define DIL_TOTAL 33554432

// d_ws layout: shorts (bf16) then floats
#define WA_OFF 0          // [blk4][mat2][half2][kc2][tap2][h64][c-chunk32] bf16
#define WO_OFF 131072     // [blk4][half2][kc2][c64][h-chunk32]
#define WD_OFF 163840     // [half2][kc2][tap2][co64][ci-chunk32]
#define SK_BYTE_OFF 360448 // fp32 [ci64][o64]

__device__ __forceinline__ short f2bf(float x) {     // RNE fp32->bf16 (prep only)
  unsigned u = __float_as_uint(x);
  return (short)((u + 0x7fffu + ((u >> 16) & 1u)) >> 16);
}
__device__ __forceinline__ short f2bf_tr(float x) {  // truncation split: 1 op
  return (short)(__float_as_uint(x) >> 16);
}
__device__ __forceinline__ float bf2f(short h) {
  return __uint_as_float(((unsigned)(unsigned short)h) << 16);
}
__device__ __forceinline__ f32x4 mfma16(s16x8 a, s16x8 b, f32x4 c) {
  return __builtin_amdgcn_mfma_f32_16x16x32_bf16(a, b, c, 0, 0, 0);
}

__global__ void prep(const float* __restrict__ sig_w, const float* __restrict__ gate_w,
                     const float* __restrict__ out_w, const float* __restrict__ dil_w,
                     const float* __restrict__ skip_w, short* __restrict__ wsS,
                     float* __restrict__ wsF) {
  const int idx = blockIdx.x * 256 + threadIdx.x;
  if (idx < 131072) {                       // WA: sig/gate conv weights
    const int inner = idx & 2047, grp = idx >> 11;
    const int tap = grp & 1, kc = (grp >> 1) & 1, half = (grp >> 2) & 1;
    const int mat = (grp >> 3) & 1, blk = grp >> 4;
    const int h = inner >> 5, c = kc * 32 + (inner & 31);
    const float* W = mat ? gate_w : sig_w;
    const float w = W[((blk * CH + h) * CH + c) * 2 + tap];
    const short hi = f2bf(w);
    wsS[WA_OFF + idx] = half ? f2bf(w - bf2f(hi)) : hi;
  } else if (idx < 163840) {                // WO: 1x1 out conv
    const int i2 = idx - 131072;
    const int inner = i2 & 2047, grp = i2 >> 11;
    const int kc = grp & 1, half = (grp >> 1) & 1, blk = grp >> 2;
    const int c = inner >> 5, h = kc * 32 + (inner & 31);
    const float w = out_w[(blk * CH + c) * CH + h];
    const short hi = f2bf(w);
    wsS[idx] = half ? f2bf(w - bf2f(hi)) : hi;
  } else if (idx < 180224) {                // WD: dilated conv
    const int i3 = idx - 163840;
    const int inner = i3 & 2047, grp = i3 >> 11;
    const int tap = grp & 1, kc = (grp >> 1) & 1, half = (grp >> 2) & 1;
    const int co = inner >> 5, ci = kc * 32 + (inner & 31);
    const float w = dil_w[(co * CH + ci) * 2 + tap];
    const short hi = f2bf(w);
    wsS[idx] = half ? f2bf(w - bf2f(hi)) : hi;
  } else if (idx < 184320) {                // SK: skip weights, fp32 transposed
    const int i4 = idx - 180224;
    const int ci = i4 >> 6, o = i4 & 63;
    wsF[i4] = skip_w[o * CH + ci];
  }
}

// Residual master: 2-component bf16 split (hi/lo in GBs), truncation splits.
// GEMM loops are (kc,tap)-outer with unroll-1 so only 4 weight frags (16 VGPR)
// are live at once -> peak regs ~100 -> 4 wg/CU with 32.5 KB LDS.
__global__ __launch_bounds__(256, 4)
void wavenet_mfma(const float* __restrict__ x,
                  const float* __restrict__ sig_b, const float* __restrict__ gate_b,
                  const float* __restrict__ out_b, const float* __restrict__ skip_b,
                  const float* __restrict__ dil_b, const short* __restrict__ wsS,
                  const float* __restrict__ wsF, float* __restrict__ out) {
  __shared__ __align__(16) short GBs[2 * 113 * GBROW];    // bf16 hi/lo [half][r=p+1][c]; shared with U

  const int tile = blockIdx.x % NTILE;
  const int b    = blockIdx.x / NTILE;
  const int t0   = tile * TT;
  const int tid  = threadIdx.x;
  const int lane = tid & 63;
  const int wv   = tid >> 6;
  const int n    = lane & 15;          // n / D-col index
  const int g4   = lane >> 4;          // quad id
  const int hbase = wv * 16;           // this wave's m-strip
  const int cch  = hbase + g4 * 4;     // this thread's 4-channel strip

  // ---- x -> GB (bf16 hi/lo, truncation split), causal zero-pad outside [0,T) ----
  for (int idx = tid; idx < CH * COLS; idx += 256) {
    const int c = idx / COLS, p = idx - c * COLS;
    const int tg = t0 - HALO + p;
    float v = 0.f;
    if (tg >= 0 && tg < TSEQ) v = x[(b * CH + c) * TSEQ + tg];
    const short hi = f2bf_tr(v);
    GBs[(p + 1) * GBROW + c] = hi;
    GBs[(113 + p + 1) * GBROW + c] = f2bf_tr(v - bf2f(hi));
  }
  if (tid < 2 * GBROW) {               // row 0 = p=-1 (zero pad)
    const int half = tid / GBROW;
    GBs[half * 113 * GBROW + (tid - half * GBROW)] = 0;
  }
  __syncthreads();

  const int lo_p = (tile == 0) ? HALO : 0;   // tile 0 keeps t<0 columns pinned to 0
  const int lbase = (hbase + n) * 32 + g4 * 8;   // A-frag lane offset

#pragma unroll 1
  for (int blk = 0; blk < NBLK; ++blk) {
    // ---- GEMM1: S,T[h=16-strip][p] via split-bf16 (HH + LH + HL) ----
    // (kc,tap)-outer, unroll 1: only 4 weight frags live at a time.
    f32x4 aS[NT], aG[NT];
#pragma unroll
    for (int j = 0; j < NT; ++j) { aS[j] = (f32x4)0.f; aG[j] = (f32x4)0.f; }
#pragma unroll 1
    for (int kt = 0; kt < 4; ++kt) {
      const int kc = kt >> 1, tap = kt & 1;
      // WA strides: tap 2048, kc 4096, half 8192, mat 16384, blk 32768
      const int wa = WA_OFF + blk * 32768 + kc * 4096 + tap * 2048 + lbase;
      const s16x8 wS0 = *(const s16x8*)&wsS[wa];
      const s16x8 wS1 = *(const s16x8*)&wsS[wa + 8192];
      const s16x8 wG0 = *(const s16x8*)&wsS[wa + 16384];
      const s16x8 wG1 = *(const s16x8*)&wsS[wa + 16384 + 8192];
      const short* bH = &GBs[(n + tap) * GBROW + g4 * 8 + kc * 32];
      const short* bL = bH + 113 * GBROW;
#pragma unroll
      for (int j = 0; j < NT; ++j) {
        const int ro = j * 16 * GBROW;
        const s16x8 bh = *(const s16x8*)(bH + ro);
        const s16x8 bl = *(const s16x8*)(bL + ro);
        aS[j] = mfma16(wS0, bh, aS[j]);
        aS[j] = mfma16(wS1, bh, aS[j]);
        aS[j] = mfma16(wS0, bl, aS[j]);
        aG[j] = mfma16(wG0, bh, aG[j]);
        aG[j] = mfma16(wG1, bh, aG[j]);
        aG[j] = mfma16(wG0, bl, aG[j]);
      }
    }
    __syncthreads();   // GEMM1 reads of GB done

    // ---- elementwise: read old-g (before overwrite!), then U over GB ----
    f32x4 gOld[NT];    // live only through GEMM2 (low-pressure phase)
    const f32x4 bs4 = *(const f32x4*)(sig_b  + blk * 64 + cch);
    const f32x4 bg4 = *(const f32x4*)(gate_b + blk * 64 + cch);
#pragma unroll
    for (int j = 0; j < NT; ++j) {
      const int r1 = j * 16 + n + 1;
      const s16x4 oh = *(const s16x4*)&GBs[r1 * GBROW + cch];
      const s16x4 ol = *(const s16x4*)&GBs[(113 + r1) * GBROW + cch];
      s16x4 uh, ul;
#pragma unroll
      for (int r = 0; r < 4; ++r) {
        gOld[j][r] = bf2f(oh[r]) + bf2f(ol[r]);
        const float s = fmaxf(aS[j][r] + bs4[r], 0.f);
        const float t = aG[j][r] + bg4[r];
        const float u = s * __builtin_amdgcn_rcpf(1.f + __expf(-t));
        const short hi = f2bf_tr(u);
        uh[r] = hi; ul[r] = f2bf_tr(u - bf2f(hi));
      }
      *(s16x4*)&GBs[r1 * GBROW + cch] = uh;
      *(s16x4*)&GBs[(113 + r1) * GBROW + cch] = ul;
    }
    __syncthreads();   // U complete

    // ---- GEMM2: dG[c=16-strip][p] = b_out + Wout * U (kc-outer, unroll 1) ----
    f32x4 aO[NT];
    const f32x4 ob4 = *(const f32x4*)(out_b + blk * 64 + cch);
#pragma unroll
    for (int j = 0; j < NT; ++j) aO[j] = ob4;
#pragma unroll 1
    for (int kc = 0; kc < 2; ++kc) {
      // WO strides: kc 2048, half 4096, blk 8192
      const int wo = WO_OFF + blk * 8192 + kc * 2048 + lbase;
      const s16x8 wO0 = *(const s16x8*)&wsS[wo];
      const s16x8 wO1 = *(const s16x8*)&wsS[wo + 4096];
      const short* uH = &GBs[(n + 1) * GBROW + g4 * 8 + kc * 32];
      const short* uL = uH + 113 * GBROW;
#pragma unroll
      for (int j = 0; j < NT; ++j) {
        const int ro = j * 16 * GBROW;
        const s16x8 uh = *(const s16x8*)(uH + ro);
        const s16x8 ul = *(const s16x8*)(uL + ro);
        aO[j] = mfma16(wO0, uh, aO[j]);
        aO[j] = mfma16(wO1, uh, aO[j]);
        aO[j] = mfma16(wO0, ul, aO[j]);
      }
    }
    __syncthreads();   // GEMM2 reads of U done

    // ---- epilogue: residual update in fp32 + re-split (hi/lo trunc) into LDS ----
#pragma unroll
    for (int j = 0; j < NT; ++j) {
      const int p = j * 16 + n;
      const f32x4 nv = (p >= lo_p) ? (f32x4)(gOld[j] + aO[j]) : gOld[j];
      s16x4 nh, nl;
#pragma unroll
      for (int r = 0; r < 4; ++r) {
        const short hi = f2bf_tr(nv[r]);
        nh[r] = hi; nl[r] = f2bf_tr(nv[r] - bf2f(hi));
      }
      *(s16x4*)&GBs[(p + 1) * GBROW + cch] = nh;
      *(s16x4*)&GBs[(113 + p + 1) * GBROW + cch] = nl;
    }
    __syncthreads();
  }

  // ---- dilated stride-2 conv (GEMM over tau) ----
  {
    s16x8 wD[2][2][2];
#pragma unroll
    for (int half = 0; half < 2; ++half)
#pragma unroll
      for (int kc = 0; kc < 2; ++kc)
#pragma unroll
        for (int tap = 0; tap < 2; ++tap)
          wD[half][kc][tap] = *(const s16x8*)&wsS[WD_OFF + ((half*2+kc)*2+tap)*2048 + lbase];
    const f32x4 db4 = *(const f32x4*)(dil_b + cch);
    const int tau0 = tile * QPT;
#pragma unroll
    for (int j = 0; j < 4; ++j) {
      const int idx = j * 16 + n;
      const int idxc = (idx < QPT) ? idx : (QPT - 1);   // clamp reads; stores masked
      f32x4 ad = db4;
      const int rbase = (6 + idxc * 2) * GBROW + g4 * 8;
#pragma unroll
      for (int kc = 0; kc < 2; ++kc)
#pragma unroll
        for (int tap = 0; tap < 2; ++tap) {
          const s16x8 bh = *(const s16x8*)&GBs[rbase + tap * GBROW + kc * 32];
          const s16x8 bl = *(const s16x8*)&GBs[113 * GBROW + rbase + tap * GBROW + kc * 32];
          ad = mfma16(wD[0][kc][tap], bh, ad);
          ad = mfma16(wD[1][kc][tap], bh, ad);
          ad = mfma16(wD[0][kc][tap], bl, ad);
        }
      const int tau = tau0 + idx;
      if (idx < QPT && tau < TOUT) {
        const int cobase = b * CH + cch;
#pragma unroll
        for (int r = 0; r < 4; ++r)
          out[(cobase + r) * TOUT + tau] = ad[r];
      }
    }
  }

  // ---- skip: 1x1 conv on t=4095 (p=73 -> row 74), hi+lo reconstruct ----
  if (tile == NTILE - 1 && wv == 0) {
    const int o = lane;
    float a = skip_b[o];
    for (int c = 0; c < CH; ++c) {
      const float g = bf2f(GBs[74 * GBROW + c]) + bf2f(GBs[(113 + 74) * GBROW + c]);
      a = fmaf(wsF[c * CH + o], g, a);
    }
    out[DIL_TOTAL + b * CH + o] = a;
  }
}

extern "C" void kernel_launch(void* const* d_in, const int* in_sizes, int n_in,
                              void* d_out, int out_size, void* d_ws, size_t ws_size,
                              hipStream_t stream) {
  const float* x      = (const float*)d_in[0];
  const float* sig_w  = (const float*)d_in[1];
  const float* sig_b  = (const float*)d_in[2];
  const float* gate_w = (const float*)d_in[3];
  const float* gate_b = (const float*)d_in[4];
  const float* out_w  = (const float*)d_in[5];
  const float* out_b  = (const float*)d_in[6];
  const float* skip_w = (const float*)d_in[7];
  const float* skip_b = (const float*)d_in[8];
  const float* dil_w  = (const float*)d_in[9];
  const float* dil_b  = (const float*)d_in[10];
  short* wsS = (short*)d_ws;
  float* wsF = (float*)((char*)d_ws + SK_BYTE_OFF);
  float* out = (float*)d_out;

  prep<<<dim3(720), dim3(256), 0, stream>>>(sig_w, gate_w, out_w, dil_w, skip_w, wsS, wsF);
  wavenet_mfma<<<dim3(256 * NTILE), dim3(256), 0, stream>>>(
      x, sig_b, gate_b, out_b, skip_b, dil_b, (const short*)wsS, (const float*)wsF, out);
}